// Round 5
// baseline (2553.934 us; speedup 1.0000x reference)
//
#include <hip/hip_runtime.h>
#include <hip/hip_bf16.h>
#include <cmath>

// Problem constants (B,S,D,H,F fixed by the reference)
#define BB  2
#define SS  2048
#define DD  2048
#define HH  16
#define DKK 128      // D / H
#define FF  8192
#define FQ  2048     // F / 4 (FFN split into quarters to bound workspace)
#define MM  4096     // B * S
#define EPSL 1e-6f

typedef __attribute__((ext_vector_type(8))) short  short8;   // 8 bf16 MFMA frag
typedef __attribute__((ext_vector_type(4))) float  floatx4;  // MFMA accumulator
typedef __hip_bfloat16 bf16t;

__device__ __forceinline__ float bits2f(ushort u) {
    return __uint_as_float(((unsigned int)u) << 16);
}
__device__ __forceinline__ ushort f2bits(float f) {
    __hip_bfloat16 h = __float2bfloat16(f);
    return *reinterpret_cast<ushort*>(&h);
}

// ---------------------------------------------------------------------------
// Input-dtype detector. If x is float32, its even-indexed u16 halves are
// mantissa bits: exponent field ~uniform -> ~39% have exp<100 or exp==0xFF.
// If x is bf16 N(0,1), even elements are real values: that count is ~0.
// ---------------------------------------------------------------------------
__global__ __launch_bounds__(256) void detect_kernel(const ushort* __restrict__ x,
                                                     int* __restrict__ flag) {
    __shared__ int cnt_s;
    if (threadIdx.x == 0) cnt_s = 0;
    __syncthreads();
    int c = 0;
#pragma unroll
    for (int i = 0; i < 16; i++) {
        const ushort v = x[(threadIdx.x * 16 + i) * 2];
        const int e = (v >> 7) & 0xFF;
        if (e == 0xFF || e < 100) c++;
    }
    atomicAdd(&cnt_s, c);
    __syncthreads();
    if (threadIdx.x == 0) *flag = (cnt_s > 512) ? 1 : 0;
}

// ---------------------------------------------------------------------------
// LayerNorm (torch semantics: mean, std ddof=1, y=g*(x-m)/(std+eps)+b).
// in_ext: input is an external tensor (dtype per flag); params g,b always
// external. Output always internal bf16.
// ---------------------------------------------------------------------------
__global__ __launch_bounds__(256) void ln_kernel(const void* __restrict__ x,
                                                 const void* __restrict__ g,
                                                 const void* __restrict__ b,
                                                 bf16t* __restrict__ out,
                                                 const int* __restrict__ flagp,
                                                 int in_ext) {
    const int fl = *flagp;
    const int row = blockIdx.x;
    const int t = threadIdx.x;

    float v[8];
    if (in_ext && fl) {
        const float* xr = (const float*)x + (size_t)row * DD;
        const float4 a4 = ((const float4*)xr)[2 * t];
        const float4 b4 = ((const float4*)xr)[2 * t + 1];
        v[0] = a4.x; v[1] = a4.y; v[2] = a4.z; v[3] = a4.w;
        v[4] = b4.x; v[5] = b4.y; v[6] = b4.z; v[7] = b4.w;
    } else {
        const ushort* xr = (const ushort*)x + (size_t)row * DD;
        union { uint4 u; ushort s[8]; } p;
        p.u = ((const uint4*)xr)[t];
#pragma unroll
        for (int i = 0; i < 8; i++) v[i] = bits2f(p.s[i]);
    }

    float sum = 0.f, sq = 0.f;
#pragma unroll
    for (int i = 0; i < 8; i++) { sum += v[i]; sq += v[i] * v[i]; }
#pragma unroll
    for (int off = 32; off > 0; off >>= 1) {
        sum += __shfl_down(sum, off);
        sq  += __shfl_down(sq, off);
    }
    __shared__ float ssum[4], ssq[4];
    const int wid = t >> 6, lane = t & 63;
    if (lane == 0) { ssum[wid] = sum; ssq[wid] = sq; }
    __syncthreads();
    if (t == 0) {
        float S = 0.f, Q = 0.f;
#pragma unroll
        for (int i = 0; i < 4; i++) { S += ssum[i]; Q += ssq[i]; }
        ssum[0] = S; ssq[0] = Q;
    }
    __syncthreads();
    const float S = ssum[0], Q = ssq[0];
    const float mean = S / (float)DD;
    float var = (Q - S * mean) / (float)(DD - 1);
    var = fmaxf(var, 0.f);
    const float inv = 1.0f / (sqrtf(var) + EPSL);

    float gv[8], bv[8];
    if (fl) {
        const float4 ga = ((const float4*)g)[2 * t], gb = ((const float4*)g)[2 * t + 1];
        const float4 ba = ((const float4*)b)[2 * t], bb4 = ((const float4*)b)[2 * t + 1];
        gv[0]=ga.x; gv[1]=ga.y; gv[2]=ga.z; gv[3]=ga.w; gv[4]=gb.x; gv[5]=gb.y; gv[6]=gb.z; gv[7]=gb.w;
        bv[0]=ba.x; bv[1]=ba.y; bv[2]=ba.z; bv[3]=ba.w; bv[4]=bb4.x; bv[5]=bb4.y; bv[6]=bb4.z; bv[7]=bb4.w;
    } else {
        union { uint4 u; ushort s[8]; } gg, bb;
        gg.u = ((const uint4*)g)[t];
        bb.u = ((const uint4*)b)[t];
#pragma unroll
        for (int i = 0; i < 8; i++) { gv[i] = bits2f(gg.s[i]); bv[i] = bits2f(bb.s[i]); }
    }

    union { uint4 u; ushort s[8]; } o;
#pragma unroll
    for (int i = 0; i < 8; i++) o.s[i] = f2bits((v[i] - mean) * inv * gv[i] + bv[i]);
    ((uint4*)((ushort*)out + (size_t)row * DD))[t] = o.u;
}

// ---------------------------------------------------------------------------
// GEMM: C[M,N] = A[M,K] @ B[K,N] (+bias) (+residual) (+ReLU)
// A: internal bf16. B: EXTERNAL weight, native [K][N], dtype per flag,
// element offset b_off, row stride Bs; transposed to [n][k] in LDS.
// res_mode: 0 none, 1 external (dtype per flag), 2 internal bf16.
// c_ext: 1 -> C dtype per flag; 0 -> internal bf16.
// vt: write C in per-(b,h)-transposed V layout (internal bf16).
// ---------------------------------------------------------------------------
__global__ __launch_bounds__(256) void gemm_bn(const bf16t* __restrict__ A,
                                               const void* __restrict__ B,
                                               long b_off, int Bs,
                                               const void* __restrict__ bias, int bias_off,
                                               const void* __restrict__ residual, int res_mode,
                                               void* __restrict__ C, int c_ext,
                                               int Nx, int Kx, int relu, int vt,
                                               const int* __restrict__ flagp) {
    __shared__ __align__(16) ushort At[128 * 32];    // [m][k]
    __shared__ __align__(16) ushort Btl[128 * 40];   // [n][k], k-stride 40 (80B, 16B-aligned)

    const int fl = *flagp;
    const int tid = threadIdx.x;
    const int wid = tid >> 6, lane = tid & 63;
    const int m16 = lane & 15, quad = lane >> 4;
    const int wr = wid >> 1, wc = wid & 1;
    const int m0 = blockIdx.y * 128, n0 = blockIdx.x * 128;

    floatx4 acc[4][4];
#pragma unroll
    for (int i = 0; i < 4; i++)
#pragma unroll
        for (int j = 0; j < 4; j++) acc[i][j] = (floatx4){0.f, 0.f, 0.f, 0.f};

    const int r_a = tid >> 2;            // A staging: 0..63 (+64)
    const int c_a = (tid & 3) * 8;
    const ushort* Au = (const ushort*)A;

    const int nk = Kx / 32;
    for (int kt = 0; kt < nk; kt++) {
        __syncthreads();
        // A tile [128][32]
#pragma unroll
        for (int half = 0; half < 2; half++) {
            const int row = r_a + half * 64;
            *(uint4*)&At[row * 32 + c_a] =
                *(const uint4*)(Au + (size_t)(m0 + row) * Kx + kt * 32 + c_a);
        }
        // B tile: transpose [32 k][128 n] -> Btl[n][k]
        if (fl) {
            const float* Bf = (const float*)B;
#pragma unroll
            for (int it = 0; it < 4; it++) {
                const int c = tid + it * 256;        // 0..1023
                const int kr = c >> 5;               // 0..31
                const int nc = (c & 31) * 4;         // 0..124
                const float4 vb = *(const float4*)(Bf + (size_t)(kt * 32 + kr) * Bs + b_off + n0 + nc);
                Btl[(nc + 0) * 40 + kr] = f2bits(vb.x);
                Btl[(nc + 1) * 40 + kr] = f2bits(vb.y);
                Btl[(nc + 2) * 40 + kr] = f2bits(vb.z);
                Btl[(nc + 3) * 40 + kr] = f2bits(vb.w);
            }
        } else {
            const ushort* Bu = (const ushort*)B;
#pragma unroll
            for (int it = 0; it < 2; it++) {
                const int c = tid + it * 256;        // 0..511
                const int kr = c >> 4;               // 0..31
                const int nc = (c & 15) * 8;         // 0..120
                union { uint4 u; ushort s[8]; } tb;
                tb.u = *(const uint4*)(Bu + (size_t)(kt * 32 + kr) * Bs + b_off + n0 + nc);
#pragma unroll
                for (int i = 0; i < 8; i++) Btl[(nc + i) * 40 + kr] = tb.s[i];
            }
        }
        __syncthreads();

        short8 af[4], bfr[4];
#pragma unroll
        for (int i = 0; i < 4; i++)
            af[i] = *(const short8*)&At[(wr * 64 + i * 16 + m16) * 32 + quad * 8];
#pragma unroll
        for (int j = 0; j < 4; j++)
            bfr[j] = *(const short8*)&Btl[(wc * 64 + j * 16 + m16) * 40 + quad * 8];
#pragma unroll
        for (int i = 0; i < 4; i++)
#pragma unroll
            for (int j = 0; j < 4; j++)
                acc[i][j] = __builtin_amdgcn_mfma_f32_16x16x32_bf16(af[i], bfr[j], acc[i][j], 0, 0, 0);
    }

    // epilogue: C/D layout col=lane&15, row=quad*4+reg (m89-verified)
#pragma unroll
    for (int i = 0; i < 4; i++) {
        const int row = m0 + wr * 64 + i * 16 + quad * 4;
#pragma unroll
        for (int j = 0; j < 4; j++) {
            const int col = n0 + wc * 64 + j * 16 + m16;
            float bb = 0.f;
            if (bias)
                bb = fl ? ((const float*)bias)[bias_off + col]
                        : bits2f(((const ushort*)bias)[bias_off + col]);
#pragma unroll
            for (int r = 0; r < 4; r++) {
                float v = acc[i][j][r] + bb;
                if (vt) {
                    const int bb2 = (row + r) >> 11, s = (row + r) & 2047;
                    const int hh2 = col >> 7, dd2 = col & 127;
                    ((ushort*)C)[((size_t)(bb2 * HH + hh2) * DKK + dd2) * SS + s] = f2bits(v);
                } else {
                    const size_t idx = (size_t)(row + r) * Nx + col;
                    if (res_mode == 1)
                        v += fl ? ((const float*)residual)[idx]
                                : bits2f(((const ushort*)residual)[idx]);
                    else if (res_mode == 2)
                        v += bits2f(((const ushort*)residual)[idx]);
                    if (relu) v = fmaxf(v, 0.f);
                    if (c_ext && fl) ((float*)C)[idx] = v;
                    else             ((ushort*)C)[idx] = f2bits(v);
                }
            }
        }
    }
}

// ---------------------------------------------------------------------------
// Flash attention (all operands internal bf16): block = (64 q-rows, h, b),
// 4 waves; online softmax; P via LDS C->A relayout. Mask all-ones -> skipped.
// ---------------------------------------------------------------------------
__global__ __launch_bounds__(256) void attn_kernel(const bf16t* __restrict__ q,
                                                   const bf16t* __restrict__ k,
                                                   const bf16t* __restrict__ vT,
                                                   bf16t* __restrict__ o) {
    __shared__ __align__(16) ushort Qt[64 * 128];
    __shared__ __align__(16) ushort Kt[64 * 128];
    __shared__ __align__(16) ushort Vt[128 * 64];
    __shared__ __align__(16) ushort Pt[4][16 * 64];

    const int tid = threadIdx.x;
    const int wid = tid >> 6, lane = tid & 63;
    const int m16 = lane & 15, quad = lane >> 4;
    const int qt = blockIdx.x, h = blockIdx.y, b = blockIdx.z;
    const int q0 = qt * 64;

    const ushort* qu = (const ushort*)q;
    const ushort* ku = (const ushort*)k;
    const ushort* vu = (const ushort*)vT;

#pragma unroll
    for (int it = 0; it < 4; it++) {
        const int c0 = tid + it * 256;
        const int r = c0 >> 4, cc = (c0 & 15) * 8;
        *(uint4*)&Qt[r * 128 + cc] =
            *(const uint4*)(qu + (size_t)(b * SS + q0 + r) * DD + h * DKK + cc);
    }

    float m_r[4], l_r[4];
    floatx4 acc_o[8];
#pragma unroll
    for (int r = 0; r < 4; r++) { m_r[r] = -1e30f; l_r[r] = 0.f; }
#pragma unroll
    for (int t = 0; t < 8; t++) acc_o[t] = (floatx4){0.f, 0.f, 0.f, 0.f};

    const float scale = 0.08838834764831845f;   // 1/sqrt(128)

    for (int kt2 = 0; kt2 < SS / 64; kt2++) {
        __syncthreads();
#pragma unroll
        for (int it = 0; it < 4; it++) {
            const int c0 = tid + it * 256;
            const int r = c0 >> 4, cc = (c0 & 15) * 8;
            *(uint4*)&Kt[r * 128 + cc] =
                *(const uint4*)(ku + (size_t)(b * SS + kt2 * 64 + r) * DD + h * DKK + cc);
            const int r2 = c0 >> 3, cc2 = (c0 & 7) * 8;
            *(uint4*)&Vt[r2 * 64 + cc2] =
                *(const uint4*)(vu + (size_t)((b * HH + h) * DKK + r2) * SS + kt2 * 64 + cc2);
        }
        __syncthreads();

        short8 af[4];
#pragma unroll
        for (int kk = 0; kk < 4; kk++)
            af[kk] = *(const short8*)&Qt[(wid * 16 + m16) * 128 + kk * 32 + quad * 8];
        floatx4 sacc[4];
#pragma unroll
        for (int j = 0; j < 4; j++) {
            sacc[j] = (floatx4){0.f, 0.f, 0.f, 0.f};
#pragma unroll
            for (int kk = 0; kk < 4; kk++) {
                short8 bfk = *(const short8*)&Kt[(j * 16 + m16) * 128 + kk * 32 + quad * 8];
                sacc[j] = __builtin_amdgcn_mfma_f32_16x16x32_bf16(af[kk], bfk, sacc[j], 0, 0, 0);
            }
        }
#pragma unroll
        for (int r = 0; r < 4; r++) {
            float s0 = sacc[0][r] * scale, s1 = sacc[1][r] * scale;
            float s2 = sacc[2][r] * scale, s3 = sacc[3][r] * scale;
            float mx = fmaxf(fmaxf(s0, s1), fmaxf(s2, s3));
#pragma unroll
            for (int off = 1; off < 16; off <<= 1) mx = fmaxf(mx, __shfl_xor(mx, off));
            const float mnew = fmaxf(m_r[r], mx);
            const float alpha = __expf(m_r[r] - mnew);
            m_r[r] = mnew;
            const float p0 = __expf(s0 - mnew), p1 = __expf(s1 - mnew);
            const float p2 = __expf(s2 - mnew), p3 = __expf(s3 - mnew);
            float rs = p0 + p1 + p2 + p3;
#pragma unroll
            for (int off = 1; off < 16; off <<= 1) rs += __shfl_xor(rs, off);
            l_r[r] = l_r[r] * alpha + rs;
#pragma unroll
            for (int t = 0; t < 8; t++) acc_o[t][r] *= alpha;
            const int prow = (quad * 4 + r) * 64;
            Pt[wid][prow + 0 * 16 + m16] = f2bits(p0);
            Pt[wid][prow + 1 * 16 + m16] = f2bits(p1);
            Pt[wid][prow + 2 * 16 + m16] = f2bits(p2);
            Pt[wid][prow + 3 * 16 + m16] = f2bits(p3);
        }
#pragma unroll
        for (int kk2 = 0; kk2 < 2; kk2++) {
            short8 ap = *(const short8*)&Pt[wid][m16 * 64 + kk2 * 32 + quad * 8];
#pragma unroll
            for (int t = 0; t < 8; t++) {
                short8 bv = *(const short8*)&Vt[(t * 16 + m16) * 64 + kk2 * 32 + quad * 8];
                acc_o[t] = __builtin_amdgcn_mfma_f32_16x16x32_bf16(ap, bv, acc_o[t], 0, 0, 0);
            }
        }
    }

    ushort* ou = (ushort*)o;
#pragma unroll
    for (int t = 0; t < 8; t++) {
#pragma unroll
        for (int r = 0; r < 4; r++) {
            const float v = acc_o[t][r] / l_r[r];
            ou[(size_t)(b * SS + q0 + wid * 16 + quad * 4 + r) * DD + h * DKK + t * 16 + m16] = f2bits(v);
        }
    }
}

// ---------------------------------------------------------------------------
// Orchestration. ws: 4 x 16 MiB slots + flag @64Mi. All internal buffers bf16.
//   ws[ 0,16): k   -> n2 (k dead after attn)
//   ws[16,32): vT  -> h-quarter (vT dead after attn)
//   ws[32,48): n   -> a (n dead after QKV)
//   ws[48,64): x1
//   d_out    : q scratch (bf16, <=16Mi fits either out dtype) -> final out
// ---------------------------------------------------------------------------
extern "C" void kernel_launch(void* const* d_in, const int* in_sizes, int n_in,
                              void* d_out, int out_size, void* d_ws, size_t ws_size,
                              hipStream_t stream) {
    const void* x   = d_in[0];
    // d_in[1] = mask (int32, all ones) — no-op in reference, skipped
    const void* wq = d_in[2];  const void* bq = d_in[3];
    const void* wk = d_in[4];  const void* bk = d_in[5];
    const void* wv = d_in[6];  const void* bv = d_in[7];
    const void* wo = d_in[8];  const void* bo = d_in[9];
    const void* w1 = d_in[10]; const void* b1 = d_in[11];
    const void* w2 = d_in[12]; const void* b2 = d_in[13];
    const void* g1 = d_in[14]; const void* lb1 = d_in[15];
    const void* g2 = d_in[16]; const void* lb2 = d_in[17];

    char* ws = (char*)d_ws;
    bf16t* k_buf  = (bf16t*)(ws);                 // [0,16M)
    bf16t* vT_buf = (bf16t*)(ws + (16u << 20));   // [16,32M)
    bf16t* n_buf  = (bf16t*)(ws + (32u << 20));   // [32,48M)
    bf16t* x1_buf = (bf16t*)(ws + (48u << 20));   // [48,64M)
    int*   flagp  = (int*)(ws + (64u << 20));
    bf16t* a_buf  = n_buf;                        // reuse n after QKV
    bf16t* n2_buf = k_buf;                        // reuse k after attn
    bf16t* h_buf  = vT_buf;                       // reuse vT after attn
    bf16t* q_buf  = (bf16t*)d_out;                // scratch until final writes

    const dim3 grDD(DD / 128, MM / 128);          // (16, 32)

    detect_kernel<<<1, 256, 0, stream>>>((const ushort*)x, flagp);

    // LN1: x -> n
    ln_kernel<<<MM, 256, 0, stream>>>(x, g1, lb1, n_buf, flagp, 1);

    // Projections (weights native [K][N], dtype per flag)
    gemm_bn<<<grDD, 256, 0, stream>>>(n_buf, wq, 0, DD, bq, 0, nullptr, 0,
                                      q_buf, 0, DD, DD, 0, 0, flagp);
    gemm_bn<<<grDD, 256, 0, stream>>>(n_buf, wk, 0, DD, bk, 0, nullptr, 0,
                                      k_buf, 0, DD, DD, 0, 0, flagp);
    gemm_bn<<<grDD, 256, 0, stream>>>(n_buf, wv, 0, DD, bv, 0, nullptr, 0,
                                      vT_buf, 0, DD, DD, 0, 1, flagp);

    // attention -> a (n slot)
    attn_kernel<<<dim3(SS / 64, HH, BB), 256, 0, stream>>>(q_buf, k_buf, vT_buf, a_buf);

    // x1 = x + a @ wo + bo -> ws slot (internal bf16); residual x external
    gemm_bn<<<grDD, 256, 0, stream>>>(a_buf, wo, 0, DD, bo, 0, x, 1,
                                      x1_buf, 0, DD, DD, 0, 0, flagp);

    // LN2: x1 -> n2
    ln_kernel<<<MM, 256, 0, stream>>>(x1_buf, g2, lb2, n2_buf, flagp, 0);

    // FFN in four F-quarters: out = x1 + relu(n2@w1+b1) @ w2 + b2
    for (int qtr = 0; qtr < 4; qtr++) {
        const long f0 = (long)qtr * FQ;
        // h = relu(n2 @ w1[:, f0:f0+FQ] + b1[f0:])  (internal bf16)
        gemm_bn<<<dim3(FQ / 128, MM / 128), 256, 0, stream>>>(
            n2_buf, w1, f0, FF, b1, (int)f0, nullptr, 0,
            h_buf, 0, FQ, DD, 1, 0, flagp);
        // qtr0: out = x1(bf16) + h@w2q + b2 ; else: out += h@w2q (ext dtype)
        gemm_bn<<<grDD, 256, 0, stream>>>(
            h_buf, w2, f0 * DD, DD, qtr == 0 ? b2 : nullptr, 0,
            qtr == 0 ? (const void*)x1_buf : (const void*)d_out, qtr == 0 ? 2 : 1,
            d_out, 1, DD, FQ, 0, 0, flagp);
    }
}

// Round 6
// 1268.110 us; speedup vs baseline: 2.0140x; 2.0140x over previous
//
#include <hip/hip_runtime.h>
#include <hip/hip_bf16.h>
#include <cmath>

// Problem constants (B,S,D,H,F fixed by the reference). Inputs are float32
// (confirmed round 5); internal compute bf16 MFMA; output float32.
#define BB  2
#define SS  2048
#define DD  2048
#define HH  16
#define DKK 128      // D / H
#define FF  8192
#define FQ  2048     // F / 4 (FFN split into quarters to bound workspace)
#define MM  4096     // B * S
#define EPSL 1e-6f

typedef __attribute__((ext_vector_type(8))) short  short8;   // 8 bf16 MFMA frag
typedef __attribute__((ext_vector_type(4))) float  floatx4;  // MFMA accumulator
typedef __hip_bfloat16 bf16t;

__device__ __forceinline__ float bits2f(ushort u) {
    return __uint_as_float(((unsigned int)u) << 16);
}
__device__ __forceinline__ ushort f2bits(float f) {
    __hip_bfloat16 h = __float2bfloat16(f);
    return *reinterpret_cast<ushort*>(&h);
}

// ---------------------------------------------------------------------------
// LayerNorm (torch semantics: mean, std ddof=1, y=g*(x-m)/(std+eps)+b).
// in_f32: input external f32; else internal bf16. Params f32. Output bf16.
// ---------------------------------------------------------------------------
__global__ __launch_bounds__(256) void ln_kernel(const void* __restrict__ x,
                                                 const float* __restrict__ g,
                                                 const float* __restrict__ b,
                                                 bf16t* __restrict__ out,
                                                 int in_f32) {
    const int row = blockIdx.x;
    const int t = threadIdx.x;

    float v[8];
    if (in_f32) {
        const float* xr = (const float*)x + (size_t)row * DD;
        const float4 a4 = ((const float4*)xr)[2 * t];
        const float4 b4 = ((const float4*)xr)[2 * t + 1];
        v[0] = a4.x; v[1] = a4.y; v[2] = a4.z; v[3] = a4.w;
        v[4] = b4.x; v[5] = b4.y; v[6] = b4.z; v[7] = b4.w;
    } else {
        const ushort* xr = (const ushort*)x + (size_t)row * DD;
        union { uint4 u; ushort s[8]; } p;
        p.u = ((const uint4*)xr)[t];
#pragma unroll
        for (int i = 0; i < 8; i++) v[i] = bits2f(p.s[i]);
    }

    float sum = 0.f, sq = 0.f;
#pragma unroll
    for (int i = 0; i < 8; i++) { sum += v[i]; sq += v[i] * v[i]; }
#pragma unroll
    for (int off = 32; off > 0; off >>= 1) {
        sum += __shfl_down(sum, off);
        sq  += __shfl_down(sq, off);
    }
    __shared__ float ssum[4], ssq[4];
    const int wid = t >> 6, lane = t & 63;
    if (lane == 0) { ssum[wid] = sum; ssq[wid] = sq; }
    __syncthreads();
    if (t == 0) {
        float S = 0.f, Q = 0.f;
#pragma unroll
        for (int i = 0; i < 4; i++) { S += ssum[i]; Q += ssq[i]; }
        ssum[0] = S; ssq[0] = Q;
    }
    __syncthreads();
    const float S = ssum[0], Q = ssq[0];
    const float mean = S / (float)DD;
    float var = (Q - S * mean) / (float)(DD - 1);
    var = fmaxf(var, 0.f);
    const float inv = 1.0f / (sqrtf(var) + EPSL);

    const float4 ga = ((const float4*)g)[2 * t], gb = ((const float4*)g)[2 * t + 1];
    const float4 ba = ((const float4*)b)[2 * t], bb4 = ((const float4*)b)[2 * t + 1];
    const float gv[8] = {ga.x, ga.y, ga.z, ga.w, gb.x, gb.y, gb.z, gb.w};
    const float bv[8] = {ba.x, ba.y, ba.z, ba.w, bb4.x, bb4.y, bb4.z, bb4.w};

    union { uint4 u; ushort s[8]; } o;
#pragma unroll
    for (int i = 0; i < 8; i++) o.s[i] = f2bits((v[i] - mean) * inv * gv[i] + bv[i]);
    ((uint4*)((ushort*)out + (size_t)row * DD))[t] = o.u;
}

// ---------------------------------------------------------------------------
// Weight transpose + f32->bf16: out[c][r] = in[r0+r][c0+c], 32x32 tiles.
// grid = (nC/32, nR/32), block (32,8).
// ---------------------------------------------------------------------------
__global__ __launch_bounds__(256) void wtrans_kernel(const float* __restrict__ in,
                                                     bf16t* __restrict__ out,
                                                     int Cs, int r0, int c0, int nR) {
    __shared__ ushort tile[32][33];
    const int tx = threadIdx.x, ty = threadIdx.y;
    const int cc = blockIdx.x * 32, rr = blockIdx.y * 32;
#pragma unroll
    for (int j = 0; j < 4; j++)
        tile[ty + j * 8][tx] = f2bits(in[(size_t)(r0 + rr + ty + j * 8) * Cs + c0 + cc + tx]);
    __syncthreads();
    ushort* op = (ushort*)out;
#pragma unroll
    for (int j = 0; j < 4; j++)
        op[(size_t)(cc + ty + j * 8) * nR + rr + tx] = tile[tx][ty + j * 8];
}

// ---------------------------------------------------------------------------
// GEMM: C[M,N] = A[M,K] @ BT[N,K]^T (+bias f32) (+residual) (+ReLU)
// A, BT internal bf16. m97 structure: global_load_lds width-16 staging,
// 128x128 tile, BK=32, 4 waves 2x2, 4x4 of mfma_f32_16x16x32_bf16.
// res_mode: 0 none, 1 external f32, 2 internal bf16. c_f32: C dtype.
// vt: write C in per-(b,h)-transposed V layout (bf16).
// ---------------------------------------------------------------------------
__global__ __launch_bounds__(256) void gemm_bt(const bf16t* __restrict__ A,
                                               const bf16t* __restrict__ BT,
                                               const float* __restrict__ bias,
                                               const void* __restrict__ residual, int res_mode,
                                               void* __restrict__ C, int c_f32,
                                               int Nx, int Kx, int relu, int vt) {
    __shared__ __align__(16) ushort At[128 * 32];
    __shared__ __align__(16) ushort Bt[128 * 32];

    const int tid = threadIdx.x;
    const int wid = tid >> 6, lane = tid & 63;
    const int m16 = lane & 15, quad = lane >> 4;
    const int wr = wid >> 1, wc = wid & 1;
    const int m0 = blockIdx.y * 128, n0 = blockIdx.x * 128;

    floatx4 acc[4][4];
#pragma unroll
    for (int i = 0; i < 4; i++)
#pragma unroll
        for (int j = 0; j < 4; j++) acc[i][j] = (floatx4){0.f, 0.f, 0.f, 0.f};

    // staging: chunk = 1024B = 16 rows x 32 bf16; lane covers 16B
    const int rc = lane >> 2, c8 = (lane & 3) * 8;
    const ushort* gA0 = (const ushort*)A  + (size_t)(m0 + rc) * Kx + c8;
    const ushort* gB0 = (const ushort*)BT + (size_t)(n0 + rc) * Kx + c8;

    const int nk = Kx / 32;
    for (int kt = 0; kt < nk; kt++) {
        __syncthreads();
#pragma unroll
        for (int cc = 0; cc < 2; cc++) {
            const int ch = wid * 2 + cc;  // wave-uniform chunk id (0..7)
            const ushort* ga = gA0 + (size_t)(ch * 16) * Kx + kt * 32;
            const ushort* gb = gB0 + (size_t)(ch * 16) * Kx + kt * 32;
            __builtin_amdgcn_global_load_lds(
                (const __attribute__((address_space(1))) void*)ga,
                (__attribute__((address_space(3))) void*)(&At[ch * 512]), 16, 0, 0);
            __builtin_amdgcn_global_load_lds(
                (const __attribute__((address_space(1))) void*)gb,
                (__attribute__((address_space(3))) void*)(&Bt[ch * 512]), 16, 0, 0);
        }
        __syncthreads();

        short8 af[4], bfr[4];
#pragma unroll
        for (int i = 0; i < 4; i++)
            af[i] = *(const short8*)&At[(wr * 64 + i * 16 + m16) * 32 + quad * 8];
#pragma unroll
        for (int j = 0; j < 4; j++)
            bfr[j] = *(const short8*)&Bt[(wc * 64 + j * 16 + m16) * 32 + quad * 8];
#pragma unroll
        for (int i = 0; i < 4; i++)
#pragma unroll
            for (int j = 0; j < 4; j++)
                acc[i][j] = __builtin_amdgcn_mfma_f32_16x16x32_bf16(af[i], bfr[j], acc[i][j], 0, 0, 0);
    }

    // epilogue: C/D layout col=lane&15, row=quad*4+reg (m89-verified)
#pragma unroll
    for (int i = 0; i < 4; i++) {
        const int row = m0 + wr * 64 + i * 16 + quad * 4;
#pragma unroll
        for (int j = 0; j < 4; j++) {
            const int col = n0 + wc * 64 + j * 16 + m16;
            const float bb = bias ? bias[col] : 0.f;
#pragma unroll
            for (int r = 0; r < 4; r++) {
                float v = acc[i][j][r] + bb;
                if (vt) {
                    const int bb2 = (row + r) >> 11, s = (row + r) & 2047;
                    const int hh2 = col >> 7, dd2 = col & 127;
                    ((ushort*)C)[((size_t)(bb2 * HH + hh2) * DKK + dd2) * SS + s] = f2bits(v);
                } else {
                    const size_t idx = (size_t)(row + r) * Nx + col;
                    if (res_mode == 1)      v += ((const float*)residual)[idx];
                    else if (res_mode == 2) v += bits2f(((const ushort*)residual)[idx]);
                    if (relu) v = fmaxf(v, 0.f);
                    if (c_f32) ((float*)C)[idx] = v;
                    else       ((ushort*)C)[idx] = f2bits(v);
                }
            }
        }
    }
}

// ---------------------------------------------------------------------------
// Flash attention: block = (64 q-rows, h, b), 4 waves; online softmax;
// P via LDS C->A relayout. LDS strides padded for conflict-free access:
// Qt/Kt 144, Vt 72, Pt 72 ushorts/row (all rows 16B-aligned).
// Mask all-ones -> skipped.
// ---------------------------------------------------------------------------
#define SQK 144
#define SV  72
#define SP  72
__global__ __launch_bounds__(256) void attn_kernel(const bf16t* __restrict__ q,
                                                   const bf16t* __restrict__ k,
                                                   const bf16t* __restrict__ vT,
                                                   bf16t* __restrict__ o) {
    __shared__ __align__(16) ushort Qt[64 * SQK];
    __shared__ __align__(16) ushort Kt[64 * SQK];
    __shared__ __align__(16) ushort Vt[128 * SV];
    __shared__ __align__(16) ushort Pt[4][16 * SP];

    const int tid = threadIdx.x;
    const int wid = tid >> 6, lane = tid & 63;
    const int m16 = lane & 15, quad = lane >> 4;
    const int qt = blockIdx.x, h = blockIdx.y, b = blockIdx.z;
    const int q0 = qt * 64;

    const ushort* qu = (const ushort*)q;
    const ushort* ku = (const ushort*)k;
    const ushort* vu = (const ushort*)vT;

#pragma unroll
    for (int it = 0; it < 4; it++) {
        const int c0 = tid + it * 256;
        const int r = c0 >> 4, cc = (c0 & 15) * 8;
        *(uint4*)&Qt[r * SQK + cc] =
            *(const uint4*)(qu + (size_t)(b * SS + q0 + r) * DD + h * DKK + cc);
    }

    float m_r[4], l_r[4];
    floatx4 acc_o[8];
#pragma unroll
    for (int r = 0; r < 4; r++) { m_r[r] = -1e30f; l_r[r] = 0.f; }
#pragma unroll
    for (int t = 0; t < 8; t++) acc_o[t] = (floatx4){0.f, 0.f, 0.f, 0.f};

    const float scale = 0.08838834764831845f;   // 1/sqrt(128)

    for (int kt2 = 0; kt2 < SS / 64; kt2++) {
        __syncthreads();
#pragma unroll
        for (int it = 0; it < 4; it++) {
            const int c0 = tid + it * 256;
            const int r = c0 >> 4, cc = (c0 & 15) * 8;
            *(uint4*)&Kt[r * SQK + cc] =
                *(const uint4*)(ku + (size_t)(b * SS + kt2 * 64 + r) * DD + h * DKK + cc);
            const int r2 = c0 >> 3, cc2 = (c0 & 7) * 8;
            *(uint4*)&Vt[r2 * SV + cc2] =
                *(const uint4*)(vu + (size_t)((b * HH + h) * DKK + r2) * SS + kt2 * 64 + cc2);
        }
        __syncthreads();

        short8 af[4];
#pragma unroll
        for (int kk = 0; kk < 4; kk++)
            af[kk] = *(const short8*)&Qt[(wid * 16 + m16) * SQK + kk * 32 + quad * 8];
        floatx4 sacc[4];
#pragma unroll
        for (int j = 0; j < 4; j++) {
            sacc[j] = (floatx4){0.f, 0.f, 0.f, 0.f};
#pragma unroll
            for (int kk = 0; kk < 4; kk++) {
                short8 bfk = *(const short8*)&Kt[(j * 16 + m16) * SQK + kk * 32 + quad * 8];
                sacc[j] = __builtin_amdgcn_mfma_f32_16x16x32_bf16(af[kk], bfk, sacc[j], 0, 0, 0);
            }
        }
#pragma unroll
        for (int r = 0; r < 4; r++) {
            float s0 = sacc[0][r] * scale, s1 = sacc[1][r] * scale;
            float s2 = sacc[2][r] * scale, s3 = sacc[3][r] * scale;
            float mx = fmaxf(fmaxf(s0, s1), fmaxf(s2, s3));
#pragma unroll
            for (int off = 1; off < 16; off <<= 1) mx = fmaxf(mx, __shfl_xor(mx, off));
            const float mnew = fmaxf(m_r[r], mx);
            const float alpha = __expf(m_r[r] - mnew);
            m_r[r] = mnew;
            const float p0 = __expf(s0 - mnew), p1 = __expf(s1 - mnew);
            const float p2 = __expf(s2 - mnew), p3 = __expf(s3 - mnew);
            float rs = p0 + p1 + p2 + p3;
#pragma unroll
            for (int off = 1; off < 16; off <<= 1) rs += __shfl_xor(rs, off);
            l_r[r] = l_r[r] * alpha + rs;
#pragma unroll
            for (int t = 0; t < 8; t++) acc_o[t][r] *= alpha;
            const int prow = (quad * 4 + r) * SP;
            Pt[wid][prow + 0 * 16 + m16] = f2bits(p0);
            Pt[wid][prow + 1 * 16 + m16] = f2bits(p1);
            Pt[wid][prow + 2 * 16 + m16] = f2bits(p2);
            Pt[wid][prow + 3 * 16 + m16] = f2bits(p3);
        }
#pragma unroll
        for (int kk2 = 0; kk2 < 2; kk2++) {
            short8 ap = *(const short8*)&Pt[wid][m16 * SP + kk2 * 32 + quad * 8];
#pragma unroll
            for (int t = 0; t < 8; t++) {
                short8 bv = *(const short8*)&Vt[(t * 16 + m16) * SV + kk2 * 32 + quad * 8];
                acc_o[t] = __builtin_amdgcn_mfma_f32_16x16x32_bf16(ap, bv, acc_o[t], 0, 0, 0);
            }
        }
    }

    ushort* ou = (ushort*)o;
#pragma unroll
    for (int t = 0; t < 8; t++) {
#pragma unroll
        for (int r = 0; r < 4; r++) {
            const float v = acc_o[t][r] / l_r[r];
            ou[(size_t)(b * SS + q0 + wid * 16 + quad * 4 + r) * DD + h * DKK + t * 16 + m16] = f2bits(v);
        }
    }
}

// ---------------------------------------------------------------------------
// Orchestration. ws: 4 x 16 MiB slots (64 MiB, proven safe). Stream order
// guarantees sequential kernel execution -> safe slot reuse.
//   S0: n        -> woT (after QKV)  -> n2 (after x1)
//   S1: k        -> x1 (after attn)
//   S2: w(q/k/v)T -> a (after attn) -> w1Tq | w2Tq (after x1)
//   S3: vT       -> h-quarter (after attn)
//   d_out: q (bf16 scratch, dead after attn) -> final f32 out
// ---------------------------------------------------------------------------
extern "C" void kernel_launch(void* const* d_in, const int* in_sizes, int n_in,
                              void* d_out, int out_size, void* d_ws, size_t ws_size,
                              hipStream_t stream) {
    const float* x   = (const float*)d_in[0];
    // d_in[1] = mask (int32, all ones) — no-op in reference, skipped
    const float* wq = (const float*)d_in[2];  const float* bq = (const float*)d_in[3];
    const float* wk = (const float*)d_in[4];  const float* bk = (const float*)d_in[5];
    const float* wv = (const float*)d_in[6];  const float* bv = (const float*)d_in[7];
    const float* wo = (const float*)d_in[8];  const float* bo = (const float*)d_in[9];
    const float* w1 = (const float*)d_in[10]; const float* b1 = (const float*)d_in[11];
    const float* w2 = (const float*)d_in[12]; const float* b2 = (const float*)d_in[13];
    const float* g1 = (const float*)d_in[14]; const float* lb1 = (const float*)d_in[15];
    const float* g2 = (const float*)d_in[16]; const float* lb2 = (const float*)d_in[17];

    char* ws = (char*)d_ws;
    bf16t* S0 = (bf16t*)(ws);
    bf16t* S1 = (bf16t*)(ws + (16u << 20));
    bf16t* S2 = (bf16t*)(ws + (32u << 20));
    bf16t* S3 = (bf16t*)(ws + (48u << 20));
    bf16t* S2b = (bf16t*)(ws + (32u << 20) + (8u << 20));  // upper half of S2

    bf16t* n_buf  = S0;
    bf16t* k_buf  = S1;
    bf16t* wT_buf = S2;      // per-projection weight transpose (8 MB)
    bf16t* vT_buf = S3;
    bf16t* q_buf  = (bf16t*)d_out;   // scratch (d_out = 33.5 MB f32)
    bf16t* a_buf  = S2;      // after attn (wT dead)
    bf16t* woT    = S0;      // after QKV (n dead)
    bf16t* x1_buf = S1;      // after attn (k dead)
    bf16t* n2_buf = S0;      // after x1 (woT dead)
    bf16t* w1Tq   = S2;      // FFN (a dead)
    bf16t* w2Tq   = S2b;
    bf16t* h_buf  = S3;      // FFN (vT dead)

    const dim3 tb(32, 8);
    const dim3 grT(DD / 32, DD / 32);             // 2048x2048 transposes
    const dim3 grDD(DD / 128, MM / 128);          // (16, 32)

    // LN1: x(f32) -> n(bf16)
    ln_kernel<<<MM, 256, 0, stream>>>(x, g1, lb1, n_buf, 1);

    // Projections: wT = w^T (bf16), then m97 GEMM
    wtrans_kernel<<<grT, tb, 0, stream>>>(wq, wT_buf, DD, 0, 0, DD);
    gemm_bt<<<grDD, 256, 0, stream>>>(n_buf, wT_buf, bq, nullptr, 0, q_buf, 0, DD, DD, 0, 0);
    wtrans_kernel<<<grT, tb, 0, stream>>>(wk, wT_buf, DD, 0, 0, DD);
    gemm_bt<<<grDD, 256, 0, stream>>>(n_buf, wT_buf, bk, nullptr, 0, k_buf, 0, DD, DD, 0, 0);
    wtrans_kernel<<<grT, tb, 0, stream>>>(wv, wT_buf, DD, 0, 0, DD);
    gemm_bt<<<grDD, 256, 0, stream>>>(n_buf, wT_buf, bv, nullptr, 0, vT_buf, 0, DD, DD, 0, 1);

    // attention -> a (S2; wT dead)
    attn_kernel<<<dim3(SS / 64, HH, BB), 256, 0, stream>>>(q_buf, k_buf, vT_buf, a_buf);

    // x1 = x + a @ wo + bo -> S1 (bf16); residual x external f32
    wtrans_kernel<<<grT, tb, 0, stream>>>(wo, woT, DD, 0, 0, DD);
    gemm_bt<<<grDD, 256, 0, stream>>>(a_buf, woT, bo, x, 1, x1_buf, 0, DD, DD, 0, 0);

    // LN2: x1(bf16) -> n2
    ln_kernel<<<MM, 256, 0, stream>>>(x1_buf, g2, lb2, n2_buf, 0);

    // FFN in four F-quarters: out = x1 + relu(n2@w1+b1) @ w2 + b2
    for (int qtr = 0; qtr < 4; qtr++) {
        const int f0 = qtr * FQ;
        // w1Tq = w1[:, f0:f0+FQ]^T (bf16 [FQ][D])
        wtrans_kernel<<<dim3(FQ / 32, DD / 32), tb, 0, stream>>>(w1, w1Tq, FF, 0, f0, DD);
        // h = relu(n2 @ w1Tq + b1[f0:]) (bf16 [M][FQ])
        gemm_bt<<<dim3(FQ / 128, MM / 128), 256, 0, stream>>>(
            n2_buf, w1Tq, b1 + f0, nullptr, 0, h_buf, 0, FQ, DD, 1, 0);
        // w2Tq = w2[f0:f0+FQ, :]^T (bf16 [D][FQ])
        wtrans_kernel<<<dim3(DD / 32, FQ / 32), tb, 0, stream>>>(w2, w2Tq, DD, f0, 0, FQ);
        // qtr0: out = x1(bf16) + h@w2Tq + b2 ; else: out += h@w2Tq (f32 in-place)
        gemm_bt<<<grDD, 256, 0, stream>>>(
            h_buf, w2Tq, qtr == 0 ? b2 : nullptr,
            qtr == 0 ? (const void*)x1_buf : (const void*)d_out, qtr == 0 ? 2 : 1,
            d_out, 1, DD, FQ, 0, 0);
    }
}